// Round 11
// baseline (99.621 us; speedup 1.0000x reference)
//
#include <hip/hip_runtime.h>
#include <hip/hip_fp16.h>

#define BN 4096
#define DIM 256
#define NBLK 32              // 4096/128 row-blocks
#define NPAIR 528            // NBLK*(NBLK+1)/2 upper-tri block pairs
#define NSLOT 32             // one partial slot per row-block
#define GRID_MAIN 256        // persistent: 1 block/CU, 2-3 pairs each
#define MARGIN_F 0.3f
#define NEG_FILL_F 1e9f
#define HP_SENT_BITS 0xBF800000  // bits of -1.0f: "no positive seen" (d^2 domain)

typedef __attribute__((ext_vector_type(8))) _Float16 f16x8;
typedef __attribute__((ext_vector_type(4))) float f32x4;

// async global->LDS, 16B per lane; LDS dest: wave-uniform base + lane*16
__device__ __forceinline__ void gld_lds16(const void* g, void* l) {
    __builtin_amdgcn_global_load_lds(
        (const __attribute__((address_space(1))) unsigned int*)g,
        (__attribute__((address_space(3))) unsigned int*)l, 16, 0, 0);
}

__device__ __forceinline__ void decode_pair(int t, int& ib, int& jb) {
    int off = 0; ib = 0;
    while (off + (NBLK - ib) <= t) { off += NBLK - ib; ++ib; }
    jb = ib + (t - off);
}

// ---------------- prep: norms (exact fp32) + red zero + fp16 panel ---------------
// Eh chunk-major: [kc = k/8][row][8 f16]. Writes are NONTEMPORAL (bypass L2) so
// tl_main's cross-XCD reads hit clean IC lines instead of remote dirty L2.
__global__ __launch_bounds__(256) void tl_prep(const float* __restrict__ E,
                                               float* __restrict__ norms,
                                               float* __restrict__ red,
                                               ushort* __restrict__ Eh) {
    const int tid  = threadIdx.x;
    const int lane = tid & 63;
    const int row  = blockIdx.x * 4 + (tid >> 6);

    float4 v = reinterpret_cast<const float4*>(E + (size_t)row * DIM)[lane];
    float f[4] = {v.x, v.y, v.z, v.w};
    ushort hb[4];
    float s = 0.0f;
    #pragma unroll
    for (int q = 0; q < 4; ++q) {
        s += f[q] * f[q];                       // norm from ORIGINAL fp32 (exact)
        hb[q] = __half_as_ushort(__float2half(f[q]));   // RN convert
    }
    // lane holds k = lane*4..lane*4+3 -> chunk kc = lane/2, half = lane&1
    const int kc = lane >> 1, half = lane & 1;
    const size_t co = (((size_t)(kc * BN + row)) << 3) + (size_t)(half * 4);
    const unsigned w0 = (unsigned)hb[0] | ((unsigned)hb[1] << 16);
    const unsigned w1 = (unsigned)hb[2] | ((unsigned)hb[3] << 16);
    unsigned* dst = reinterpret_cast<unsigned*>(Eh + co);
    __builtin_nontemporal_store(w0, dst);
    __builtin_nontemporal_store(w1, dst + 1);

    #pragma unroll
    for (int m = 32; m; m >>= 1) s += __shfl_xor(s, m, 64);
    if (lane == 0) norms[row] = s;
    if (blockIdx.x == 0 && tid < 3) red[tid] = 0.0f;  // [0]=sum [1]=cnt [2]=ticket
}

// ---------------- main: persistent blocks, A-resident fp16 MFMA Gram -------------
// 256 blocks, each owns pairs {2b, 2b+1} (+ 512+b for b<16), ib-major so A-tile
// (64 KB LDS) persists across pairs sharing ib; B (64 KB) restages per pair with
// the prefetch for pair p+1 issued before pair p's epilogue. Selection on d^2.
// Collision-free partial stores: row-part -> slot jb, col-part -> slot ib.
__global__ __launch_bounds__(256) void tl_main(const ushort* __restrict__ Eh,
                                               const int* __restrict__ labels,
                                               const float* __restrict__ norms,
                                               float* __restrict__ pHP,
                                               float* __restrict__ pHN) {
    __shared__ __align__(16) ushort smA[32768];   // 64 KB: chunks [kc 0..31][m 0..127]
    __shared__ __align__(16) ushort smB[32768];   // 64 KB
    __shared__ int comb[512];                     // 2 KB epilogue scratch

    const int tid  = threadIdx.x;
    const int lane = tid & 63;
    const int wave = tid >> 6;
    const int wy = wave >> 1, wx = wave & 1;
    const int quad = lane >> 4, l15 = lane & 15;
    const int bid  = blockIdx.x;
    const int nmine = 2 + ((bid < NPAIR - 2 * GRID_MAIN) ? 1 : 0);

    auto stageA = [&](int ib) {
        #pragma unroll
        for (int s = 0; s < 16; ++s) {
            const int idx = s * 256 + tid;           // 4096 16B chunks
            const int kc = idx >> 7, m = idx & 127;
            gld_lds16(Eh + (((size_t)(kc * BN + ib * 128 + m)) << 3), &smA[idx << 3]);
        }
    };
    auto stageB = [&](int jb) {
        #pragma unroll
        for (int s = 0; s < 16; ++s) {
            const int idx = s * 256 + tid;
            const int kc = idx >> 7, m = idx & 127;
            gld_lds16(Eh + (((size_t)(kc * BN + jb * 128 + m)) << 3), &smB[idx << 3]);
        }
    };

    int curIb = -1;
    for (int pi = 0; pi < nmine; ++pi) {
        const int t = (pi < 2) ? (2 * bid + pi) : (2 * GRID_MAIN + bid);
        int ib, jb; decode_pair(t, ib, jb);
        const int i0 = ib * 128, j0 = jb * 128;

        if (pi == 0) { stageA(ib); curIb = ib; stageB(jb); }
        __syncthreads();                         // staged tiles ready

        f32x4 acc[4][4];
        #pragma unroll
        for (int r = 0; r < 4; ++r)
            #pragma unroll
            for (int c = 0; c < 4; ++c)
                acc[r][c] = (f32x4){0.f, 0.f, 0.f, 0.f};

        #pragma unroll
        for (int t8 = 0; t8 < 8; ++t8) {         // 8 K-steps of 32, no barriers
            f16x8 a[4], b[4];
            #pragma unroll
            for (int r = 0; r < 4; ++r) {
                const int mi = wy * 64 + r * 16 + l15;
                a[r] = *reinterpret_cast<const f16x8*>(&smA[(((t8 * 4 + quad) * 128) + mi) * 8]);
            }
            #pragma unroll
            for (int c = 0; c < 4; ++c) {
                const int ni = wx * 64 + c * 16 + l15;
                b[c] = *reinterpret_cast<const f16x8*>(&smB[(((t8 * 4 + quad) * 128) + ni) * 8]);
            }
            #pragma unroll
            for (int c = 0; c < 4; ++c)
                #pragma unroll
                for (int r = 0; r < 4; ++r)
                    acc[r][c] = __builtin_amdgcn_mfma_f32_16x16x32_f16(a[r], b[c], acc[r][c], 0, 0, 0);
        }
        __syncthreads();                         // all waves done reading smB (and smA)

        // ---- gathers for this pair's epilogue (issued BEFORE prefetch so their
        //      waitcnt doesn't force the prefetch to drain) ----
        const int rowBase = i0 + wy * 64;
        const int colBase = j0 + wx * 64;
        float nrow[4][4]; int lrow[4][4];
        #pragma unroll
        for (int r = 0; r < 4; ++r)
            #pragma unroll
            for (int e = 0; e < 4; ++e) {
                const int g = rowBase + r * 16 + quad * 4 + e;
                nrow[r][e] = norms[g];
                lrow[r][e] = labels[g];
            }
        float ncol[4]; int lcol[4];
        #pragma unroll
        for (int c = 0; c < 4; ++c) {
            const int g = colBase + c * 16 + l15;
            ncol[c] = norms[g];
            lcol[c] = labels[g];
        }

        // ---- prefetch next pair's tiles (flies during epilogue math) ----
        if (pi + 1 < nmine) {
            const int tn = (pi + 1 < 2) ? (2 * bid + pi + 1) : (2 * GRID_MAIN + bid);
            int ibn, jbn; decode_pair(tn, ibn, jbn);
            if (ibn != curIb) { stageA(ibn); curIb = ibn; }
            stageB(jbn);
        }

        // ---- epilogue: d^2 select (sqrt deferred to tl_reduce) ----
        float rmax2[4][4], rmin2[4][4], cmax2[4], cmin2[4];
        #pragma unroll
        for (int r = 0; r < 4; ++r)
            #pragma unroll
            for (int e = 0; e < 4; ++e) { rmax2[r][e] = -1.0f; rmin2[r][e] = NEG_FILL_F; }
        #pragma unroll
        for (int c = 0; c < 4; ++c) { cmax2[c] = -1.0f; cmin2[c] = NEG_FILL_F; }

        #pragma unroll
        for (int c = 0; c < 4; ++c) {
            const int gcol = colBase + c * 16 + l15;
            #pragma unroll
            for (int r = 0; r < 4; ++r) {
                #pragma unroll
                for (int e = 0; e < 4; ++e) {
                    const int grow = rowBase + r * 16 + quad * 4 + e;
                    float d2 = fmaxf(nrow[r][e] + ncol[c] - 2.0f * acc[r][c][e], 0.0f);
                    if (lrow[r][e] == lcol[c]) {
                        if (grow != gcol) {
                            rmax2[r][e] = fmaxf(rmax2[r][e], d2);
                            cmax2[c]    = fmaxf(cmax2[c], d2);
                        }
                    } else {
                        rmin2[r][e] = fminf(rmin2[r][e], d2);
                        cmin2[c]    = fminf(cmin2[c], d2);
                    }
                }
            }
        }

        #pragma unroll
        for (int m = 1; m <= 8; m <<= 1) {       // row stats across lane bits 0..3
            #pragma unroll
            for (int r = 0; r < 4; ++r)
                #pragma unroll
                for (int e = 0; e < 4; ++e) {
                    rmax2[r][e] = fmaxf(rmax2[r][e], __shfl_xor(rmax2[r][e], m, 64));
                    rmin2[r][e] = fminf(rmin2[r][e], __shfl_xor(rmin2[r][e], m, 64));
                }
        }
        #pragma unroll
        for (int m = 16; m <= 32; m <<= 1) {     // col stats across quads
            #pragma unroll
            for (int c = 0; c < 4; ++c) {
                cmax2[c] = fmaxf(cmax2[c], __shfl_xor(cmax2[c], m, 64));
                cmin2[c] = fminf(cmin2[c], __shfl_xor(cmin2[c], m, 64));
            }
        }

        // block combine in comb[] (CU-local atomics; signed-int max orders -1.0f
        // sentinel correctly over {-1} U [0,inf)), then PLAIN global stores.
        int*      srhp = comb;                                   // [128]
        unsigned* srhn = reinterpret_cast<unsigned*>(comb + 128);
        int*      schp = comb + 256;
        unsigned* schn = reinterpret_cast<unsigned*>(comb + 384);
        if (tid < 128) {
            srhp[tid] = (int)HP_SENT_BITS;
            srhn[tid] = __float_as_uint(NEG_FILL_F);
            schp[tid] = (int)HP_SENT_BITS;
            schn[tid] = __float_as_uint(NEG_FILL_F);
        }
        __syncthreads();
        if (l15 == 0) {   // lanes 0,16,32,48 hold row results for their quad
            #pragma unroll
            for (int r = 0; r < 4; ++r)
                #pragma unroll
                for (int e = 0; e < 4; ++e) {
                    const int lr = wy * 64 + r * 16 + quad * 4 + e;
                    atomicMax(&srhp[lr], __float_as_int(rmax2[r][e]));
                    atomicMin(&srhn[lr], __float_as_uint(rmin2[r][e]));
                }
        }
        if (quad == 0) {  // lanes 0..15 hold col results
            #pragma unroll
            for (int c = 0; c < 4; ++c) {
                const int lc = wx * 64 + c * 16 + l15;
                atomicMax(&schp[lc], __float_as_int(cmax2[c]));
                atomicMin(&schn[lc], __float_as_uint(cmin2[c]));
            }
        }
        __syncthreads();
        if (tid < 128) {
            const float rp = __int_as_float(srhp[tid]);
            const float rn = __uint_as_float(srhn[tid]);
            const float cp = __int_as_float(schp[tid]);
            const float cn = __uint_as_float(schn[tid]);
            if (ib == jb) {
                pHP[(size_t)jb * BN + i0 + tid] = fmaxf(rp, cp);   // diagonal
                pHN[(size_t)jb * BN + i0 + tid] = fminf(rn, cn);
            } else {
                pHP[(size_t)jb * BN + i0 + tid] = rp;   // row-part -> slot jb
                pHN[(size_t)jb * BN + i0 + tid] = rn;
                pHP[(size_t)ib * BN + j0 + tid] = cp;   // col-part -> slot ib
                pHN[(size_t)ib * BN + j0 + tid] = cn;
            }
        }
        // next iteration's pre-compute __syncthreads() protects comb reuse
    }
}

// ------- reduce: fold 32 slots per row, sqrt once, accumulate, last block final --
__global__ __launch_bounds__(256) void tl_reduce(const float* __restrict__ pHP,
                                                 const float* __restrict__ pHN,
                                                 float* __restrict__ red,
                                                 float* __restrict__ out) {
    const int i = blockIdx.x * 256 + threadIdx.x;    // one row per thread
    float hp2 = -1.0f, hn2 = NEG_FILL_F;
    #pragma unroll
    for (int s = 0; s < NSLOT; ++s) {
        hp2 = fmaxf(hp2, pHP[(size_t)s * BN + i]);   // coalesced per wave
        hn2 = fminf(hn2, pHN[(size_t)s * BN + i]);
    }
    const bool valid = (hp2 >= 0.0f) && (hn2 < NEG_FILL_F);  // has_pos && has_neg
    const float hp = sqrtf(fmaxf(hp2, 0.0f));        // sqrt deferred from tl_main
    const float hn = sqrtf(hn2);
    const float per = fmaxf(hp - hn + MARGIN_F, 0.0f);
    float s_ = valid ? per : 0.0f;
    float c_ = valid ? 1.0f : 0.0f;
    #pragma unroll
    for (int m = 32; m; m >>= 1) {
        s_ += __shfl_xor(s_, m, 64);
        c_ += __shfl_xor(c_, m, 64);
    }
    __shared__ float as_[4], ac_[4];
    const int wid = threadIdx.x >> 6;
    if ((threadIdx.x & 63) == 0) { as_[wid] = s_; ac_[wid] = c_; }
    __syncthreads();
    if (threadIdx.x == 0) {
        const float S = as_[0] + as_[1] + as_[2] + as_[3];
        const float C = ac_[0] + ac_[1] + ac_[2] + ac_[3];
        atomicAdd(&red[0], S);
        atomicAdd(&red[1], C);
        __threadfence();
        const unsigned ticket = atomicAdd(reinterpret_cast<unsigned*>(&red[2]), 1u);
        if (ticket == gridDim.x - 1) {               // last block finalizes
            const float S2 = atomicAdd(&red[0], 0.0f);   // atomic read (RMW-ordered)
            const float C2 = atomicAdd(&red[1], 0.0f);
            out[0] = (C2 > 0.0f) ? (S2 / fmaxf(C2, 1.0f)) : 0.0f;
        }
    }
}

extern "C" void kernel_launch(void* const* d_in, const int* in_sizes, int n_in,
                              void* d_out, int out_size, void* d_ws, size_t ws_size,
                              hipStream_t stream) {
    const float* E      = (const float*)d_in[0];
    const int*   labels = (const int*)d_in[1];

    float*  ws    = (float*)d_ws;
    float*  norms = ws;                            // [4096] f32
    float*  red   = ws + 4096;                     // [3] f32 (sum, cnt, ticket)
    float*  pHP   = ws + 8192;                     // [32][4096] f32 = 512 KB
    float*  pHN   = ws + 8192 + NSLOT * BN;        // [32][4096] f32 = 512 KB
    ushort* Eh    = (ushort*)(ws + 8192 + 2 * NSLOT * BN);  // [32][4096][8] f16 = 2 MB

    tl_prep<<<BN / 4, 256, 0, stream>>>(E, norms, red, Eh);
    tl_main<<<GRID_MAIN, 256, 0, stream>>>(Eh, labels, norms, pHP, pHN);
    tl_reduce<<<BN / 256, 256, 0, stream>>>(pHP, pHN, red, (float*)d_out);
}